// Round 1
// baseline (1449.849 us; speedup 1.0000x reference)
//
#include <hip/hip_runtime.h>
#include <cstdint>
#include <cstddef>

namespace {

constexpr int B = 8;
constexpr int NSEQ = 1024;
constexpr int C = 768;
constexpr int H = 12;
constexpr int D = 64;
constexpr int N3 = 2304;          // 3*C
constexpr float SCALE = 0.125f;   // 64^-0.5

constexpr size_t QKV_ELEMS = (size_t)B * H * NSEQ * D;   // 6291456

// ---------------------------------------------------------------------------
// Generic tiled fp32 GEMM: out = A[M,K] @ W[K,N] + bias[N]
// 64x64 output tile, K-step 16, 256 threads, 4x4 micro-tile per thread.
// MODE 0: scatter output into q/k/v [3][B,H,N,D] at `out`
// MODE 1: plain row-major [M,N]
// ---------------------------------------------------------------------------
template<int MODE>
__global__ __launch_bounds__(256)
void gemm_k(const float* __restrict__ A, const float* __restrict__ W,
            const float* __restrict__ bias, float* __restrict__ out,
            int M, int N, int K)
{
  // pad 68: row stride 272B keeps float4 16B-aligned; (kk*68+m)%32 = (4kk+m)%32
  // -> worst 2-way on stores (free per m136), conflict-free b128 reads.
  __shared__ float As[16][68];   // [k][m]
  __shared__ float Bs[16][68];   // [k][n]
  const int tid = threadIdx.x;
  const int tx = tid & 15;       // n-group
  const int ty = tid >> 4;       // m-group
  const int m0 = blockIdx.y * 64;
  const int n0 = blockIdx.x * 64;
  float acc[4][4] = {};

  for (int k0 = 0; k0 < K; k0 += 16) {
    {
      const int kk = tid & 15;
      const int mmb = tid >> 4;        // 0..15 (+r*16)
      #pragma unroll
      for (int r = 0; r < 4; ++r)
        As[kk][mmb + r*16] = A[(size_t)(m0 + mmb + r*16)*K + (k0 + kk)];
      const int nn = tid & 63;
      const int kb = tid >> 6;         // 0..3 (+r*4)
      #pragma unroll
      for (int r = 0; r < 4; ++r)
        Bs[kb + r*4][nn] = W[(size_t)(k0 + kb + r*4)*N + (n0 + nn)];
    }
    __syncthreads();
    #pragma unroll
    for (int kk = 0; kk < 16; ++kk) {
      const float4 a4 = *(const float4*)&As[kk][ty*4];
      const float4 b4 = *(const float4*)&Bs[kk][tx*4];
      const float av[4] = {a4.x, a4.y, a4.z, a4.w};
      const float bv[4] = {b4.x, b4.y, b4.z, b4.w};
      #pragma unroll
      for (int i = 0; i < 4; ++i)
        #pragma unroll
        for (int j = 0; j < 4; ++j)
          acc[i][j] = fmaf(av[i], bv[j], acc[i][j]);
    }
    __syncthreads();
  }

  #pragma unroll
  for (int i = 0; i < 4; ++i) {
    const int m = m0 + ty*4 + i;
    #pragma unroll
    for (int j = 0; j < 4; ++j) {
      const int n = n0 + tx*4 + j;
      const float val = acc[i][j] + bias[n];
      if (MODE == 0) {
        // n = which*768 + h*64 + d ; m = b*1024 + ns
        const int which = n / C;
        const int cc = n - which * C;
        const int h = cc >> 6;
        const int d = cc & 63;
        const int b = m >> 10;
        const int ns = m & 1023;
        out[(size_t)which * QKV_ELEMS + (((size_t)b*H + h)*NSEQ + ns)*D + d] = val;
      } else {
        out[(size_t)m * N + n] = val;
      }
    }
  }
}

// ---------------------------------------------------------------------------
// Attention: one block = (bh, 8 query rows). Full score rows in LDS (fp32),
// exact softmax, stream attn_weights to global, then PV.
// LDS: 32KB scores + 17KB K-tile + 2.2KB Q-tile = 52KB -> 3 blocks/CU.
// ---------------------------------------------------------------------------
__global__ __launch_bounds__(256)
void attn_k(const float* __restrict__ q, const float* __restrict__ k,
            const float* __restrict__ v, float* __restrict__ attnw,
            float* __restrict__ aout)
{
  __shared__ float sc[8][1024];   // score rows (later: probabilities)
  __shared__ float kt[64][68];    // K tile [j][d], pad 68 for b128 reads
  __shared__ float qt[8][68];     // Q tile [i][d]
  const int tid = threadIdx.x;
  const int bh = blockIdx.y;
  const int q0 = blockIdx.x * 8;
  const size_t base = (size_t)bh * NSEQ * D;

  // load Q tile (512 elems, 2/thread)
  #pragma unroll
  for (int r = 0; r < 2; ++r) {
    const int e = tid + r*256;
    const int i = e >> 6, d = e & 63;
    qt[i][d] = q[base + (size_t)(q0 + i)*D + d];
  }

  const int jg = tid & 63;
  const int ig = tid >> 6;   // wave id 0..3

  // ---- scores = Q @ K^T * scale ----
  for (int j0 = 0; j0 < NSEQ; j0 += 64) {
    __syncthreads();                       // protect kt reuse (also covers qt 1st iter)
    #pragma unroll
    for (int r = 0; r < 16; ++r) {
      const int e = tid + r*256;
      const int j = e >> 6, d = e & 63;
      kt[j][d] = k[base + (size_t)(j0 + j)*D + d];
    }
    __syncthreads();
    const int i0 = ig * 2;
    float acc0 = 0.f, acc1 = 0.f;
    #pragma unroll
    for (int dg = 0; dg < 16; ++dg) {
      const float4 kv = *(const float4*)&kt[jg][dg*4];   // conflict-free b128
      const float4 qa = *(const float4*)&qt[i0][dg*4];   // wave-uniform broadcast
      const float4 qb = *(const float4*)&qt[i0+1][dg*4];
      acc0 = fmaf(qa.x, kv.x, acc0); acc0 = fmaf(qa.y, kv.y, acc0);
      acc0 = fmaf(qa.z, kv.z, acc0); acc0 = fmaf(qa.w, kv.w, acc0);
      acc1 = fmaf(qb.x, kv.x, acc1); acc1 = fmaf(qb.y, kv.y, acc1);
      acc1 = fmaf(qb.z, kv.z, acc1); acc1 = fmaf(qb.w, kv.w, acc1);
    }
    sc[i0][j0 + jg]   = acc0 * SCALE;
    sc[i0+1][j0 + jg] = acc1 * SCALE;
  }
  __syncthreads();

  // ---- softmax (exact: max-subtract), write attn_weights ----
  {
    const int wave = tid >> 6, lane = tid & 63;
    #pragma unroll
    for (int rr = 0; rr < 2; ++rr) {
      const int i = wave*2 + rr;
      float mx = -3.0e38f;
      for (int c = lane; c < NSEQ; c += 64) mx = fmaxf(mx, sc[i][c]);
      #pragma unroll
      for (int off = 32; off > 0; off >>= 1) mx = fmaxf(mx, __shfl_xor(mx, off));
      float s = 0.f;
      for (int c = lane; c < NSEQ; c += 64) {
        const float e = __expf(sc[i][c] - mx);
        sc[i][c] = e;
        s += e;
      }
      #pragma unroll
      for (int off = 32; off > 0; off >>= 1) s += __shfl_xor(s, off);
      const float inv = 1.f / s;
      float* wrow = attnw + ((size_t)bh * NSEQ + q0 + i) * NSEQ;
      for (int c = lane; c < NSEQ; c += 64) {
        const float p = sc[i][c] * inv;
        sc[i][c] = p;
        wrow[c] = p;            // coalesced 256B per wave-store
      }
    }
  }
  __syncthreads();

  // ---- PV: out[i][d] = sum_j p[i][j] * v[j][d] ----
  {
    const int d = tid & 63;
    const int i0 = (tid >> 6) * 2;
    float acc0 = 0.f, acc1 = 0.f;
    for (int j = 0; j < NSEQ; j += 4) {
      const float4 pa = *(const float4*)&sc[i0][j];     // broadcast b128
      const float4 pb = *(const float4*)&sc[i0+1][j];
      const float v0 = v[base + (size_t)(j+0)*D + d];   // coalesced, L2-hot
      const float v1 = v[base + (size_t)(j+1)*D + d];
      const float v2 = v[base + (size_t)(j+2)*D + d];
      const float v3 = v[base + (size_t)(j+3)*D + d];
      acc0 = fmaf(pa.x, v0, acc0); acc0 = fmaf(pa.y, v1, acc0);
      acc0 = fmaf(pa.z, v2, acc0); acc0 = fmaf(pa.w, v3, acc0);
      acc1 = fmaf(pb.x, v0, acc1); acc1 = fmaf(pb.y, v1, acc1);
      acc1 = fmaf(pb.z, v2, acc1); acc1 = fmaf(pb.w, v3, acc1);
    }
    const int b = bh / H, h = bh - b*H;
    aout[((size_t)b*NSEQ + q0 + i0    )*C + h*D + d] = acc0;
    aout[((size_t)b*NSEQ + q0 + i0 + 1)*C + h*D + d] = acc1;
  }
}

} // namespace

extern "C" void kernel_launch(void* const* d_in, const int* in_sizes, int n_in,
                              void* d_out, int out_size, void* d_ws, size_t ws_size,
                              hipStream_t stream)
{
  const float* x      = (const float*)d_in[0];
  const float* qkv_w  = (const float*)d_in[1];
  const float* qkv_b  = (const float*)d_in[2];
  const float* proj_w = (const float*)d_in[3];
  const float* proj_b = (const float*)d_in[4];

  float* out   = (float*)d_out;                       // [8,1024,768]
  float* attnw = out + (size_t)B * NSEQ * C;          // [8,12,1024,1024]

  // workspace: q,k,v [B,H,N,D] + attn_out [B,N,C]  = 100.7 MB
  float* ws   = (float*)d_ws;
  float* wsq  = ws;
  float* wsk  = ws + QKV_ELEMS;
  float* wsv  = ws + 2*QKV_ELEMS;
  float* wsao = ws + 3*QKV_ELEMS;

  // 1) QKV projection, scatter to [3][B,H,N,D]
  gemm_k<0><<<dim3(N3/64, (B*NSEQ)/64), 256, 0, stream>>>(
      x, qkv_w, qkv_b, wsq, B*NSEQ, N3, C);

  // 2) attention: scores -> softmax -> attn_weights out + PV
  attn_k<<<dim3(NSEQ/8, B*H), 256, 0, stream>>>(wsq, wsk, wsv, attnw, wsao);

  // 3) output projection
  gemm_k<1><<<dim3(C/64, (B*NSEQ)/64), 256, 0, stream>>>(
      wsao, proj_w, proj_b, out, B*NSEQ, C, C);
}

// Round 2
// 266.620 us; speedup vs baseline: 5.4379x; 5.4379x over previous
//
#include <hip/hip_runtime.h>
#include <cstdint>
#include <cstddef>

namespace {

constexpr int B = 8, NSEQ = 1024, C = 768, H = 12, D = 64, N3 = 2304;
constexpr float SCALE = 0.125f;
constexpr size_t QKV_ELEMS = (size_t)B * H * NSEQ * D;   // 6291456 per tensor

using f32x4 = __attribute__((ext_vector_type(4))) float;
using s16x8 = __attribute__((ext_vector_type(8))) short;

__device__ __forceinline__ unsigned short f2bf(float f) {
  union { float f; uint32_t u; } v; v.f = f;
  const uint32_t r = v.u + 0x7FFFu + ((v.u >> 16) & 1u);   // RNE
  return (unsigned short)(r >> 16);
}
__device__ __forceinline__ float bf2f(unsigned short s) {
  union { uint32_t u; float f; } v; v.u = ((uint32_t)s) << 16;
  return v.f;
}
__device__ __forceinline__ void gload_lds16(const void* g, void* l) {
  __builtin_amdgcn_global_load_lds(
      (const __attribute__((address_space(1))) uint32_t*)g,
      (__attribute__((address_space(3))) uint32_t*)l, 16, 0, 0);
}

// ---------------------------------------------------------------------------
// x -> bf16 (row-major passthrough)
// ---------------------------------------------------------------------------
__global__ void cvt_x(const float* __restrict__ x, unsigned short* __restrict__ xb, int n4) {
  const int stride = gridDim.x * 256;
  for (int idx = blockIdx.x * 256 + threadIdx.x; idx < n4; idx += stride) {
    const float4 v = ((const float4*)x)[idx];
    ushort4 o;
    o.x = f2bf(v.x); o.y = f2bf(v.y); o.z = f2bf(v.z); o.w = f2bf(v.w);
    ((ushort4*)xb)[idx] = o;
  }
}

// ---------------------------------------------------------------------------
// W[K][N] fp32 -> Wt[N][K] bf16   (32x32 LDS tile transpose)
// ---------------------------------------------------------------------------
__global__ void transp_cvt(const float* __restrict__ w, unsigned short* __restrict__ wt,
                           int K, int N) {
  __shared__ float t[32][33];
  const int n0 = blockIdx.x << 5, k0 = blockIdx.y << 5;
  const int tid = threadIdx.x;
  #pragma unroll
  for (int r = 0; r < 4; ++r) {
    const int e = (r << 8) + tid;
    const int kk = e >> 5, nn = e & 31;
    t[kk][nn] = w[(size_t)(k0 + kk) * N + n0 + nn];
  }
  __syncthreads();
  #pragma unroll
  for (int r = 0; r < 4; ++r) {
    const int e = (r << 8) + tid;
    const int nn = e >> 5, kk = e & 31;
    wt[(size_t)(n0 + nn) * K + k0 + kk] = f2bf(t[kk][nn]);
  }
}

// ---------------------------------------------------------------------------
// bf16 MFMA GEMM: out = A[M][768] @ Wt[N][768]^T + bias
// 128x128 tile, BK=64, 4 waves (2x2), each wave 64x64 (4x4 frags 16x16x32).
// LDS linear + XOR swizzle via pre-permuted global source (rule #21).
// MODE 0: scatter q/k bf16 [bh][n][d] and v^T bf16 [bh][d][n]
// MODE 1: fp32 row-major out
// ---------------------------------------------------------------------------
template<int MODE>
__global__ __launch_bounds__(256, 2)
void gemm_bf16(const unsigned short* __restrict__ A,
               const unsigned short* __restrict__ Wt,
               const float* __restrict__ bias,
               unsigned short* __restrict__ qp, unsigned short* __restrict__ kp,
               unsigned short* __restrict__ vt, float* __restrict__ out32,
               int M, int N) {
  constexpr int K = 768;
  __shared__ short As[128 * 64];
  __shared__ short Bs[128 * 64];
  const int tid = threadIdx.x;
  const int wid = tid >> 6, lane = tid & 63;
  const int wm = wid >> 1, wn = wid & 1;
  const int lg = lane >> 4, lr = lane & 15;
  const int m0 = blockIdx.y << 7, n0 = blockIdx.x << 7;

  f32x4 acc[4][4] = {};

  for (int k0 = 0; k0 < K; k0 += 64) {
    __syncthreads();
    // stage 16KB A + 16KB B: 1024 chunks of 16B each; 4 issues/thread each.
    #pragma unroll
    for (int r = 0; r < 4; ++r) {
      const int c = (r << 8) + tid;
      const int row = c >> 3, g8 = c & 7;
      const int gp = g8 ^ (row & 7);                 // pre-permuted source
      const int ldsoff = (((r << 8) + (wid << 6)) << 3);  // wave-uniform, shorts
      gload_lds16(A + (size_t)(m0 + row) * K + k0 + (gp << 3), (void*)(As + ldsoff));
      gload_lds16(Wt + (size_t)(n0 + row) * K + k0 + (gp << 3), (void*)(Bs + ldsoff));
    }
    __syncthreads();
    #pragma unroll
    for (int kc = 0; kc < 2; ++kc) {
      s16x8 af[4], bf[4];
      #pragma unroll
      for (int i = 0; i < 4; ++i) {
        const int ra = (wm << 6) + (i << 4) + lr;
        const int ca = ((kc << 2) + lg) ^ (ra & 7);
        af[i] = *(const s16x8*)(As + (ra << 6) + (ca << 3));
        const int rb = (wn << 6) + (i << 4) + lr;
        const int cb = ((kc << 2) + lg) ^ (rb & 7);
        bf[i] = *(const s16x8*)(Bs + (rb << 6) + (cb << 3));
      }
      #pragma unroll
      for (int i = 0; i < 4; ++i)
        #pragma unroll
        for (int j = 0; j < 4; ++j)
          acc[i][j] = __builtin_amdgcn_mfma_f32_16x16x32_bf16(af[i], bf[j], acc[i][j], 0, 0, 0);
    }
  }

  // epilogue: C frag lane mapping: col = lr, row = lg*4 + reg (m89-verified)
  #pragma unroll
  for (int i = 0; i < 4; ++i) {
    const int m = m0 + (wm << 6) + (i << 4) + (lg << 2);
    #pragma unroll
    for (int j = 0; j < 4; ++j) {
      const int n = n0 + (wn << 6) + (j << 4) + lr;
      const float bv = bias[n];
      if (MODE == 0) {
        const int which = (n >= 1536) ? 2 : (n >= 768 ? 1 : 0);
        const int hh = (n - which * 768) >> 6;
        const int d = n & 63;
        const int b = m >> 10, ns = m & 1023;
        const size_t bh = (size_t)b * H + hh;
        if (which < 2) {
          unsigned short* dst = (which == 0 ? qp : kp) + (bh * NSEQ + ns) * D + d;
          #pragma unroll
          for (int rg = 0; rg < 4; ++rg)
            dst[(size_t)rg * D] = f2bf(acc[i][j][rg] + bv);
        } else {
          ushort4 pk;
          pk.x = f2bf(acc[i][j][0] + bv);
          pk.y = f2bf(acc[i][j][1] + bv);
          pk.z = f2bf(acc[i][j][2] + bv);
          pk.w = f2bf(acc[i][j][3] + bv);
          *(ushort4*)(vt + (bh * D + d) * NSEQ + ns) = pk;   // ns % 4 == 0
        }
      } else {
        float* dst = out32 + (size_t)m * N + n;
        #pragma unroll
        for (int rg = 0; rg < 4; ++rg)
          dst[(size_t)rg * N] = acc[i][j][rg] + bv;
      }
    }
  }
}

// ---------------------------------------------------------------------------
// Attention: block = (bh, 16 q-rows), 4 waves.
//  QK^T MFMA -> scores bf16 in LDS -> exact softmax (e=exp(s-m) kept
//  unnormalized, 1/sum folded into epilogues) -> coalesced fp32 attnw write
//  -> PV MFMA (A-frags straight from LDS, B-frags from swizzled V^T tile).
// LDS: 33KB scores + 8KB K/V tile + 64B -> 3 blocks/CU.
// ---------------------------------------------------------------------------
__global__ __launch_bounds__(256, 3)
void attn_mfma(const unsigned short* __restrict__ qg,
               const unsigned short* __restrict__ kg,
               const unsigned short* __restrict__ vtg,
               float* __restrict__ attnw,
               unsigned short* __restrict__ aout) {
  __shared__ short sc[16][1032];   // bf16 scores -> e values
  __shared__ short kv[64 * 64];    // K tile [j][d] / V^T tile [d][j], swizzled
  __shared__ float invs[16];
  const int tid = threadIdx.x;
  const int wid = tid >> 6, lane = tid & 63;
  const int lg = lane >> 4, lr = lane & 15;
  const int bh = blockIdx.y;
  const int q0 = blockIdx.x << 4;
  const size_t kvbase = (size_t)bh * NSEQ * D;

  // Q fragments (A operand): lane holds row = lr, k = kc*32 + lg*8 + e
  s16x8 qf[2];
  #pragma unroll
  for (int kc = 0; kc < 2; ++kc)
    qf[kc] = *(const s16x8*)(qg + kvbase + (size_t)(q0 + lr) * D + (kc << 5) + (lg << 3));

  // ---- scores ----
  for (int j0 = 0; j0 < NSEQ; j0 += 64) {
    __syncthreads();
    #pragma unroll
    for (int r = 0; r < 2; ++r) {
      const int c = (r << 8) + tid;
      const int row = c >> 3, g8 = c & 7;
      gload_lds16(kg + kvbase + (size_t)(j0 + row) * D + ((g8 ^ (row & 7)) << 3),
                  (void*)(kv + (((r << 8) + (wid << 6)) << 3)));
    }
    __syncthreads();
    f32x4 cacc = {};
    const int krow = (wid << 4) + lr;   // local key row this lane serves as B col
    #pragma unroll
    for (int kc = 0; kc < 2; ++kc) {
      const int cg = ((kc << 2) + lg) ^ (krow & 7);
      const s16x8 kf = *(const s16x8*)(kv + (krow << 6) + (cg << 3));
      cacc = __builtin_amdgcn_mfma_f32_16x16x32_bf16(qf[kc], kf, cacc, 0, 0, 0);
    }
    const int jglob = j0 + (wid << 4) + lr;
    #pragma unroll
    for (int rg = 0; rg < 4; ++rg)
      sc[(lg << 2) + rg][jglob] = (short)f2bf(cacc[rg] * SCALE);
  }
  __syncthreads();

  // ---- softmax: row r handled by 16-thread group ----
  {
    const int row = tid >> 4, ql = tid & 15;
    float mx = -3.0e38f;
    #pragma unroll
    for (int c = 0; c < 8; ++c) {
      const s16x8 v = *(const s16x8*)(&sc[row][(ql << 3) + (c << 7)]);
      #pragma unroll
      for (int e = 0; e < 8; ++e) mx = fmaxf(mx, bf2f((unsigned short)v[e]));
    }
    #pragma unroll
    for (int off = 8; off > 0; off >>= 1) mx = fmaxf(mx, __shfl_xor(mx, off, 16));
    float s = 0.f;
    #pragma unroll
    for (int c = 0; c < 8; ++c) {
      s16x8 v = *(s16x8*)(&sc[row][(ql << 3) + (c << 7)]);
      #pragma unroll
      for (int e = 0; e < 8; ++e) {
        const float ev = __expf(bf2f((unsigned short)v[e]) - mx);
        s += ev;
        v[e] = (short)f2bf(ev);
      }
      *(s16x8*)(&sc[row][(ql << 3) + (c << 7)]) = v;
    }
    #pragma unroll
    for (int off = 8; off > 0; off >>= 1) s += __shfl_xor(s, off, 16);
    if (ql == 0) invs[row] = 1.0f / s;
  }
  __syncthreads();

  // ---- attn_weights: fully coalesced float4 stores ----
  {
    float* wbase = attnw + ((size_t)bh * NSEQ + q0) * NSEQ;
    #pragma unroll
    for (int r = 0; r < 16; ++r) {
      const float iv = invs[r];
      const ushort4 e4 = *(const ushort4*)(&sc[r][tid << 2]);
      float4 o;
      o.x = bf2f(e4.x) * iv; o.y = bf2f(e4.y) * iv;
      o.z = bf2f(e4.z) * iv; o.w = bf2f(e4.w) * iv;
      *(float4*)(wbase + (size_t)r * NSEQ + (tid << 2)) = o;
    }
  }

  // ---- PV: wave w owns d-frag w; A-frags read straight from sc ----
  f32x4 oacc = {};
  for (int j0 = 0; j0 < NSEQ; j0 += 64) {
    __syncthreads();
    #pragma unroll
    for (int r = 0; r < 2; ++r) {
      const int c = (r << 8) + tid;
      const int row = c >> 3, g8 = c & 7;   // row = d
      gload_lds16(vtg + (size_t)bh * D * NSEQ + (size_t)row * NSEQ + j0 + ((g8 ^ (row & 7)) << 3),
                  (void*)(kv + (((r << 8) + (wid << 6)) << 3)));
    }
    __syncthreads();
    const int drow = (wid << 4) + lr;       // local d row this lane serves as B col
    #pragma unroll
    for (int kc = 0; kc < 2; ++kc) {
      const s16x8 pa = *(const s16x8*)(&sc[lr][j0 + (kc << 5) + (lg << 3)]);
      const int cg = ((kc << 2) + lg) ^ (drow & 7);
      const s16x8 vf = *(const s16x8*)(kv + (drow << 6) + (cg << 3));
      oacc = __builtin_amdgcn_mfma_f32_16x16x32_bf16(pa, vf, oacc, 0, 0, 0);
    }
  }
  {
    const int b = bh / H, hh = bh - b * H;
    const int d = (wid << 4) + lr;
    #pragma unroll
    for (int rg = 0; rg < 4; ++rg) {
      const int i = (lg << 2) + rg;
      aout[((size_t)b * NSEQ + q0 + i) * C + hh * D + d] = f2bf(oacc[rg] * invs[i]);
    }
  }
}

} // namespace

extern "C" void kernel_launch(void* const* d_in, const int* in_sizes, int n_in,
                              void* d_out, int out_size, void* d_ws, size_t ws_size,
                              hipStream_t stream) {
  const float* x      = (const float*)d_in[0];
  const float* qkv_w  = (const float*)d_in[1];
  const float* qkv_b  = (const float*)d_in[2];
  const float* proj_w = (const float*)d_in[3];
  const float* proj_b = (const float*)d_in[4];

  float* out   = (float*)d_out;                      // [8,1024,768] fp32
  float* attnw = out + (size_t)B * NSEQ * C;         // [8,12,1024,1024] fp32

  unsigned short* xb   = (unsigned short*)d_ws;             // [8192][768]
  unsigned short* wtq  = xb   + (size_t)8192 * 768;         // [2304][768]
  unsigned short* wtp  = wtq  + (size_t)2304 * 768;         // [768][768]
  unsigned short* qp   = wtp  + (size_t)768 * 768;          // [96][1024][64]
  unsigned short* kp   = qp   + QKV_ELEMS;
  unsigned short* vtp  = kp   + QKV_ELEMS;                  // [96][64][1024]
  unsigned short* wsao = vtp  + QKV_ELEMS;                  // [8192][768]

  cvt_x<<<1024, 256, 0, stream>>>(x, xb, (int)((size_t)8192 * 768 / 4));
  transp_cvt<<<dim3(N3 / 32, C / 32), 256, 0, stream>>>(qkv_w, wtq, C, N3);
  transp_cvt<<<dim3(C / 32, C / 32), 256, 0, stream>>>(proj_w, wtp, C, C);

  gemm_bf16<0><<<dim3(N3 / 128, 8192 / 128), 256, 0, stream>>>(
      xb, wtq, qkv_b, qp, kp, vtp, nullptr, 8192, N3);

  attn_mfma<<<dim3(NSEQ / 16, B * H), 256, 0, stream>>>(qp, kp, vtp, attnw, wsao);

  gemm_bf16<1><<<dim3(C / 128, 8192 / 128), 256, 0, stream>>>(
      wsao, wtp, proj_b, nullptr, nullptr, nullptr, out, 8192, C);
}